// Round 2
// baseline (398.603 us; speedup 1.0000x reference)
//
#include <hip/hip_runtime.h>
#include <cstdint>

#define NB 8
#define NN 2048
#define DD 1024
#define DD2 2048
#define BK 64

typedef short short8 __attribute__((ext_vector_type(8)));
typedef float floatx4 __attribute__((ext_vector_type(4)));

// fp32 -> bf16 round-to-nearest-even (inputs finite)
__device__ __forceinline__ unsigned short f2bf(float f) {
    unsigned int u = __float_as_uint(f);
    u += 0x7fffu + ((u >> 16) & 1u);
    return (unsigned short)(u >> 16);
}
__device__ __forceinline__ float bf2f(unsigned short h) {
    return __uint_as_float(((unsigned int)h) << 16);
}

// async global->LDS, 16B per lane. LDS dest is wave-uniform base + lane*16.
__device__ __forceinline__ void async_copy16(const void* g, void* l) {
    __builtin_amdgcn_global_load_lds(
        (__attribute__((address_space(1))) void*)(uintptr_t)g,
        (__attribute__((address_space(3))) void*)(unsigned int)(uintptr_t)l,
        16, 0, 0);
}

// ---------------------------------------------------------------------------
// Kernel 1: per-row L2 norm of x0; write xn (bf16) + norms (fp32).
// ---------------------------------------------------------------------------
__global__ __launch_bounds__(256) void k_norm(const float* __restrict__ x,
                                              unsigned short* __restrict__ xn,
                                              float* __restrict__ norms) {
    int row  = blockIdx.x * 4 + (threadIdx.x >> 6);
    int lane = threadIdx.x & 63;
    const float* xr = x + (size_t)row * DD2;
    float4 v[4];
    float s = 0.f;
#pragma unroll
    for (int i = 0; i < 4; i++) {
        v[i] = ((const float4*)xr)[lane + i * 64];
        s += v[i].x * v[i].x + v[i].y * v[i].y + v[i].z * v[i].z + v[i].w * v[i].w;
    }
#pragma unroll
    for (int off = 32; off >= 1; off >>= 1) s += __shfl_xor(s, off, 64);
    float nrm = sqrtf(s + 1e-8f);
    float inv = 1.0f / nrm;
    if (lane == 0) norms[row] = nrm;
    unsigned short* xnr = xn + (size_t)row * DD;
#pragma unroll
    for (int i = 0; i < 4; i++) {
        ushort4 o;
        o.x = f2bf(v[i].x * inv);
        o.y = f2bf(v[i].y * inv);
        o.z = f2bf(v[i].z * inv);
        o.w = f2bf(v[i].w * inv);
        ((ushort4*)xnr)[lane + i * 64] = o;
    }
}

// ---------------------------------------------------------------------------
// Kernel 2: transpose xn (bf16) -> xnt[b][d][n] (bf16), 64x64 LDS tiles.
// ---------------------------------------------------------------------------
__global__ __launch_bounds__(256) void k_transpose(const unsigned short* __restrict__ xn,
                                                   unsigned short* __restrict__ xnt) {
    __shared__ unsigned short tile[64 * 68];
    int b  = blockIdx.y;
    int t  = blockIdx.x;       // 0..511 = 32 n-tiles x 16 d-tiles
    int n0 = (t >> 4) * 64, d0 = (t & 15) * 64;
    int tid = threadIdx.x;
    int r  = tid >> 4;         // 0..15
    int c4 = tid & 15;         // 0..15
    const unsigned short* xb = xn + (size_t)b * NN * DD;
#pragma unroll
    for (int p = 0; p < 4; p++) {
        int n = p * 16 + r;
        ushort4 v = *(const ushort4*)&xb[(size_t)(n0 + n) * DD + d0 + c4 * 4];
        tile[(c4 * 4 + 0) * 68 + n] = v.x;
        tile[(c4 * 4 + 1) * 68 + n] = v.y;
        tile[(c4 * 4 + 2) * 68 + n] = v.z;
        tile[(c4 * 4 + 3) * 68 + n] = v.w;
    }
    __syncthreads();
    unsigned short* ob = xnt + (size_t)b * DD * NN;
#pragma unroll
    for (int p = 0; p < 4; p++) {
        int d = p * 16 + r;
        ushort4 o;
        o.x = tile[d * 68 + c4 * 4 + 0];
        o.y = tile[d * 68 + c4 * 4 + 1];
        o.z = tile[d * 68 + c4 * 4 + 2];
        o.w = tile[d * 68 + c4 * 4 + 3];
        *(ushort4*)&ob[(size_t)(d0 + d) * NN + n0 + c4 * 4] = o;
    }
}

// ---------------------------------------------------------------------------
// Shared GEMM core (m97-style): C[128x128] += A[128xK] * B[128xK]^T.
// ---------------------------------------------------------------------------
__device__ __forceinline__ void stage_tile(const unsigned short* gbase, int ld,
                                           unsigned short* lds, int w, int lane) {
    int rgrp = lane >> 3;
    int slot = lane & 7;
    int sw   = slot ^ rgrp;
#pragma unroll
    for (int j = 0; j < 4; j++) {
        int r = j * 32 + w * 8 + rgrp;
        const unsigned short* g = gbase + (size_t)r * ld + sw * 8;
        unsigned short* l = lds + (j * 32 + w * 8) * BK;
        async_copy16((void*)g, (void*)l);
    }
}

__device__ __forceinline__ short8 read_frag(const unsigned short* lds, int row, int g) {
    int slot = g ^ (row & 7);
    return *(const short8*)(lds + row * BK + slot * 8);
}

__device__ __forceinline__ void gemm_core(const unsigned short* __restrict__ Ag, int lda,
                                          const unsigned short* __restrict__ Bg, int ldb,
                                          int kIters,
                                          unsigned short* As, unsigned short* Bs,
                                          floatx4 acc[4][4]) {
    int tid  = threadIdx.x;
    int w    = tid >> 6, lane = tid & 63;
    int wr   = (w >> 1) * 64, wc = (w & 1) * 64;
    int lrow = lane & 15, quad = lane >> 4;
    for (int kt = 0; kt < kIters; kt++) {
        __syncthreads();
        stage_tile(Ag + kt * BK, lda, As, w, lane);
        stage_tile(Bg + kt * BK, ldb, Bs, w, lane);
        __syncthreads();
#pragma unroll
        for (int s = 0; s < 2; s++) {
            short8 af[4], bf[4];
#pragma unroll
            for (int t = 0; t < 4; t++) af[t] = read_frag(As, wr + t * 16 + lrow, s * 4 + quad);
#pragma unroll
            for (int t = 0; t < 4; t++) bf[t] = read_frag(Bs, wc + t * 16 + lrow, s * 4 + quad);
#pragma unroll
            for (int ti = 0; ti < 4; ti++)
#pragma unroll
                for (int tj = 0; tj < 4; tj++)
                    acc[ti][tj] = __builtin_amdgcn_mfma_f32_16x16x32_bf16(
                        af[ti], bf[tj], acc[ti][tj], 0, 0, 0);
        }
    }
}

// ---------------------------------------------------------------------------
// Kernel 3: attn'[b][n][m] = tril(sp)[n][m] * cosim * norm_m  (bf16).
// LDS round-trip epilogue: coalesced dwordx4 stores, float4 sp/norm loads.
// ---------------------------------------------------------------------------
__global__ __launch_bounds__(256) void k_cosim(const unsigned short* __restrict__ xn,
                                               const float* __restrict__ sp,
                                               const float* __restrict__ norms,
                                               unsigned short* __restrict__ attn) {
    __shared__ __attribute__((aligned(16))) unsigned short As[128 * BK];
    __shared__ __attribute__((aligned(16))) unsigned short Bs[128 * BK];
    int b = blockIdx.y;
    int p = blockIdx.x;                 // 0..135 -> (nt, mt), mt<=nt
    int nt = 0;
    while ((nt + 1) * (nt + 2) / 2 <= p) nt++;
    int mt = p - nt * (nt + 1) / 2;
    int n0 = nt * 128, m0 = mt * 128;
    const unsigned short* xb = xn + (size_t)b * NN * DD;

    floatx4 acc[4][4];
#pragma unroll
    for (int i = 0; i < 4; i++)
#pragma unroll
        for (int j = 0; j < 4; j++) acc[i][j] = (floatx4)0.0f;

    gemm_core(xb + (size_t)n0 * DD, DD, xb + (size_t)m0 * DD, DD, DD / BK, As, Bs, acc);

    int tid = threadIdx.x, w = tid >> 6, lane = tid & 63;
    int wr = (w >> 1) * 64, wc = (w & 1) * 64;
    int col = lane & 15, quad = lane >> 4;
    unsigned short* ep = As;            // 64 rows x 128 cols bf16 = 16 KB, reused
    const float* spb = sp;
    const float* nmb = norms + (size_t)b * NN;
    unsigned short* ab = attn + (size_t)b * NN * NN;

#pragma unroll
    for (int chunk = 0; chunk < 2; chunk++) {
        int R0 = chunk * 64;
        __syncthreads();                // prior As readers done
        if (wr == R0) {                 // two waves own these 64 rows
#pragma unroll
            for (int ti = 0; ti < 4; ti++)
#pragma unroll
                for (int tj = 0; tj < 4; tj++)
#pragma unroll
                    for (int r = 0; r < 4; r++) {
                        int lr = ti * 16 + quad * 4 + r;       // 0..63
                        int mm = wc + tj * 16 + col;           // 0..127
                        int sg = (mm >> 3) ^ (lr & 7);         // XOR group swizzle
                        ep[lr * 128 + sg * 8 + (mm & 7)] = f2bf(acc[ti][tj][r]);
                    }
        }
        __syncthreads();
        // cooperative masked-scale-store: 64 rows x 8 segs of 16, 2 units/thread
#pragma unroll
        for (int i = 0; i < 2; i++) {
            int u = tid + 256 * i;
            int lr = u >> 3, seg = u & 7;
            int n = n0 + R0 + lr;
            int mb = m0 + seg * 16;
            short8 v0 = *(const short8*)&ep[lr * 128 + (((2 * seg) ^ (lr & 7)) * 8)];
            short8 v1 = *(const short8*)&ep[lr * 128 + (((2 * seg + 1) ^ (lr & 7)) * 8)];
            float4 s4[4], nm4[4];
#pragma unroll
            for (int q = 0; q < 4; q++) {
                s4[q]  = *(const float4*)&spb[(size_t)n * NN + mb + q * 4];
                nm4[q] = *(const float4*)&nmb[mb + q * 4];
            }
            const float* sf = (const float*)s4;
            const float* nf = (const float*)nm4;
            short8 o0, o1;
#pragma unroll
            for (int j = 0; j < 8; j++) {
                float c0 = bf2f((unsigned short)v0[j]);
                float c1 = bf2f((unsigned short)v1[j]);
                float r0 = (mb + j     <= n) ? sf[j]     * nf[j]     * c0 : 0.0f;
                float r1 = (mb + 8 + j <= n) ? sf[8 + j] * nf[8 + j] * c1 : 0.0f;
                o0[j] = (short)f2bf(r0);
                o1[j] = (short)f2bf(r1);
            }
            *(short8*)&ab[(size_t)n * NN + mb]     = o0;
            *(short8*)&ab[(size_t)n * NN + mb + 8] = o1;
        }
    }
}

// ---------------------------------------------------------------------------
// Kernel 4: out[b][n][d] = (attn'[b][n][:K] . xnt[b][d][:K]) * x1[b][n][d].
// Pair-balanced: each block does tiles {15-p, p} -> uniform 34 BK-iters.
// XCD swizzle: dt = q>>6 so the 8 dt-blocks sharing an attn panel have the
// same q%8 (same XCD) -> A-panel L2 reuse.
// ---------------------------------------------------------------------------
__global__ __launch_bounds__(256) void k_ctx(const unsigned short* __restrict__ attn,
                                             const unsigned short* __restrict__ xnt,
                                             const float* __restrict__ x,
                                             float* __restrict__ out) {
    __shared__ __attribute__((aligned(16))) unsigned short As[128 * BK];
    __shared__ __attribute__((aligned(16))) unsigned short Bs[128 * BK];
    int q = blockIdx.x;                 // 0..511
    int g = q & 63, dt = q >> 6;
    int b = g >> 3, p = g & 7;

    int tid = threadIdx.x, w = tid >> 6, lane = tid & 63;
    int wr = (w >> 1) * 64, wc = (w & 1) * 64;
    int col = lane & 15, quad = lane >> 4;
    int d0 = dt * 128;

#pragma unroll
    for (int t = 0; t < 2; t++) {
        int nt = t == 0 ? (15 - p) : p;
        int n0 = nt * 128;
        const unsigned short* Ab = attn + (size_t)b * NN * NN + (size_t)n0 * NN;
        const unsigned short* Bb = xnt + (size_t)b * DD * NN + (size_t)d0 * NN;

        floatx4 acc[4][4];
#pragma unroll
        for (int i = 0; i < 4; i++)
#pragma unroll
            for (int j = 0; j < 4; j++) acc[i][j] = (floatx4)0.0f;

        gemm_core(Ab, NN, Bb, NN, (nt + 1) * 2, As, Bs, acc);

#pragma unroll
        for (int ti = 0; ti < 4; ti++)
#pragma unroll
            for (int tj = 0; tj < 4; tj++)
#pragma unroll
                for (int r = 0; r < 4; r++) {
                    int n = n0 + wr + ti * 16 + quad * 4 + r;
                    int d = d0 + wc + tj * 16 + col;
                    float x1 = x[((size_t)b * NN + n) * DD2 + DD + d];
                    out[((size_t)b * NN + n) * DD + d] = acc[ti][tj][r] * x1;
                }
    }
}

extern "C" void kernel_launch(void* const* d_in, const int* in_sizes, int n_in,
                              void* d_out, int out_size, void* d_ws, size_t ws_size,
                              hipStream_t stream) {
    const float* x  = (const float*)d_in[0];
    const float* sp = (const float*)d_in[1];
    float* out = (float*)d_out;

    unsigned short* xn   = (unsigned short*)d_ws;                      // 33.5 MB
    unsigned short* xnt  = xn + (size_t)NB * NN * DD;                  // 33.5 MB
    unsigned short* attn = xnt + (size_t)NB * NN * DD;                 // 67 MB
    float* norms = (float*)(attn + (size_t)NB * NN * NN);              // 64 KB

    hipLaunchKernelGGL(k_norm,      dim3(NB * NN / 4), dim3(256), 0, stream, x, xn, norms);
    hipLaunchKernelGGL(k_transpose, dim3(512, NB),     dim3(256), 0, stream, xn, xnt);
    hipLaunchKernelGGL(k_cosim,     dim3(136, NB),     dim3(256), 0, stream, xn, sp, norms, attn);
    hipLaunchKernelGGL(k_ctx,       dim3(512),         dim3(256), 0, stream, attn, xnt, x, out);
}

// Round 3
// 381.104 us; speedup vs baseline: 1.0459x; 1.0459x over previous
//
#include <hip/hip_runtime.h>
#include <cstdint>

#define NB 8
#define NN 2048
#define DD 1024
#define DD2 2048
#define BK 64

typedef short short8 __attribute__((ext_vector_type(8)));
typedef float floatx4 __attribute__((ext_vector_type(4)));

// fp32 -> bf16 round-to-nearest-even (inputs finite)
__device__ __forceinline__ unsigned short f2bf(float f) {
    unsigned int u = __float_as_uint(f);
    u += 0x7fffu + ((u >> 16) & 1u);
    return (unsigned short)(u >> 16);
}

// async global->LDS, 16B per lane. LDS dest is wave-uniform base + lane*16.
__device__ __forceinline__ void async_copy16(const void* g, void* l) {
    __builtin_amdgcn_global_load_lds(
        (__attribute__((address_space(1))) void*)(uintptr_t)g,
        (__attribute__((address_space(3))) void*)(unsigned int)(uintptr_t)l,
        16, 0, 0);
}

// ---------------------------------------------------------------------------
// Kernel 1: per-row L2 norm of x0; write xn (bf16) + norms (fp32).
// ---------------------------------------------------------------------------
__global__ __launch_bounds__(256) void k_norm(const float* __restrict__ x,
                                              unsigned short* __restrict__ xn,
                                              float* __restrict__ norms) {
    int row  = blockIdx.x * 4 + (threadIdx.x >> 6);
    int lane = threadIdx.x & 63;
    const float* xr = x + (size_t)row * DD2;
    float4 v[4];
    float s = 0.f;
#pragma unroll
    for (int i = 0; i < 4; i++) {
        v[i] = ((const float4*)xr)[lane + i * 64];
        s += v[i].x * v[i].x + v[i].y * v[i].y + v[i].z * v[i].z + v[i].w * v[i].w;
    }
#pragma unroll
    for (int off = 32; off >= 1; off >>= 1) s += __shfl_xor(s, off, 64);
    float nrm = sqrtf(s + 1e-8f);
    float inv = 1.0f / nrm;
    if (lane == 0) norms[row] = nrm;
    unsigned short* xnr = xn + (size_t)row * DD;
#pragma unroll
    for (int i = 0; i < 4; i++) {
        ushort4 o;
        o.x = f2bf(v[i].x * inv);
        o.y = f2bf(v[i].y * inv);
        o.z = f2bf(v[i].z * inv);
        o.w = f2bf(v[i].w * inv);
        ((ushort4*)xnr)[lane + i * 64] = o;
    }
}

// ---------------------------------------------------------------------------
// Kernel 2: transpose xn (bf16) -> xnt[b][d][n] (bf16), 64x64 LDS tiles.
// ---------------------------------------------------------------------------
__global__ __launch_bounds__(256) void k_transpose(const unsigned short* __restrict__ xn,
                                                   unsigned short* __restrict__ xnt) {
    __shared__ unsigned short tile[64 * 68];
    int b  = blockIdx.y;
    int t  = blockIdx.x;       // 0..511 = 32 n-tiles x 16 d-tiles
    int n0 = (t >> 4) * 64, d0 = (t & 15) * 64;
    int tid = threadIdx.x;
    int r  = tid >> 4;         // 0..15
    int c4 = tid & 15;         // 0..15
    const unsigned short* xb = xn + (size_t)b * NN * DD;
#pragma unroll
    for (int p = 0; p < 4; p++) {
        int n = p * 16 + r;
        ushort4 v = *(const ushort4*)&xb[(size_t)(n0 + n) * DD + d0 + c4 * 4];
        tile[(c4 * 4 + 0) * 68 + n] = v.x;
        tile[(c4 * 4 + 1) * 68 + n] = v.y;
        tile[(c4 * 4 + 2) * 68 + n] = v.z;
        tile[(c4 * 4 + 3) * 68 + n] = v.w;
    }
    __syncthreads();
    unsigned short* ob = xnt + (size_t)b * DD * NN;
#pragma unroll
    for (int p = 0; p < 4; p++) {
        int d = p * 16 + r;
        ushort4 o;
        o.x = tile[d * 68 + c4 * 4 + 0];
        o.y = tile[d * 68 + c4 * 4 + 1];
        o.z = tile[d * 68 + c4 * 4 + 2];
        o.w = tile[d * 68 + c4 * 4 + 3];
        *(ushort4*)&ob[(size_t)(d0 + d) * NN + n0 + c4 * 4] = o;
    }
}

// ---------------------------------------------------------------------------
// Double-buffered GEMM core: C[128x128] += A[128xK] * B[128xK]^T.
// ONE raw s_barrier per iter; stage(k+1) issued right after the barrier into
// the other buffer, latency covered by iter k's ds_read+MFMA. Manual
// s_waitcnt: vmcnt(0) waits only own staging batch (nothing newer in flight
// at that point); lgkmcnt(0) closes the WAR hazard on buffer reuse.
// ---------------------------------------------------------------------------
__device__ __forceinline__ void stage_tile(const unsigned short* gbase, int ld,
                                           unsigned short* lds, int w, int lane) {
    int rgrp = lane >> 3;
    int slot = lane & 7;
    int sw   = slot ^ rgrp;              // XOR slot swizzle (frag reads <=2-way)
#pragma unroll
    for (int j = 0; j < 4; j++) {
        int r = j * 32 + w * 8 + rgrp;
        const unsigned short* g = gbase + (size_t)r * ld + sw * 8;
        unsigned short* l = lds + (j * 32 + w * 8) * BK;   // wave-uniform base
        async_copy16((void*)g, (void*)l);
    }
}

__device__ __forceinline__ short8 read_frag(const unsigned short* lds, int row, int g) {
    int slot = g ^ (row & 7);
    return *(const short8*)(lds + row * BK + slot * 8);
}

__device__ __forceinline__ void gemm_core(const unsigned short* __restrict__ Ag, int lda,
                                          const unsigned short* __restrict__ Bg, int ldb,
                                          int kIters,
                                          unsigned short* As0, unsigned short* Bs0,
                                          unsigned short* As1, unsigned short* Bs1,
                                          floatx4 acc[4][4]) {
    int tid  = threadIdx.x;
    int w    = tid >> 6, lane = tid & 63;
    int wr   = (w >> 1) * 64, wc = (w & 1) * 64;
    int lrow = lane & 15, quad = lane >> 4;

    stage_tile(Ag, lda, As0, w, lane);             // prologue: stage iter 0
    stage_tile(Bg, ldb, Bs0, w, lane);

    for (int kt = 0; kt < kIters; kt++) {
        unsigned short* Ac = (kt & 1) ? As1 : As0;
        unsigned short* Bc = (kt & 1) ? Bs1 : Bs0;
        unsigned short* An = (kt & 1) ? As0 : As1;
        unsigned short* Bn = (kt & 1) ? Bs0 : Bs1;
        // own staging of iter kt complete + all waves' reads of iter kt-1
        // consumed -> safe to read Ac/Bc and overwrite An/Bn after barrier.
        asm volatile("s_waitcnt vmcnt(0) lgkmcnt(0)\n\ts_barrier" ::: "memory");
        if (kt + 1 < kIters) {                     // prefetch flies during MFMA
            stage_tile(Ag + (size_t)(kt + 1) * BK, lda, An, w, lane);
            stage_tile(Bg + (size_t)(kt + 1) * BK, ldb, Bn, w, lane);
        }
#pragma unroll
        for (int s = 0; s < 2; s++) {
            short8 af[4], bf[4];
#pragma unroll
            for (int t = 0; t < 4; t++) af[t] = read_frag(Ac, wr + t * 16 + lrow, s * 4 + quad);
#pragma unroll
            for (int t = 0; t < 4; t++) bf[t] = read_frag(Bc, wc + t * 16 + lrow, s * 4 + quad);
#pragma unroll
            for (int ti = 0; ti < 4; ti++)
#pragma unroll
                for (int tj = 0; tj < 4; tj++)
                    acc[ti][tj] = __builtin_amdgcn_mfma_f32_16x16x32_bf16(
                        af[ti], bf[tj], acc[ti][tj], 0, 0, 0);
        }
    }
}

// ---------------------------------------------------------------------------
// Kernel 3: attn'[b][n][m] = tril(sp)[n][m] * cosim * norm_m  (bf16).
// Direct-store epilogue (low VGPR).
// ---------------------------------------------------------------------------
__global__ __launch_bounds__(256) void k_cosim(const unsigned short* __restrict__ xn,
                                               const float* __restrict__ sp,
                                               const float* __restrict__ norms,
                                               unsigned short* __restrict__ attn) {
    __shared__ __attribute__((aligned(16))) unsigned short As0[128 * BK];
    __shared__ __attribute__((aligned(16))) unsigned short Bs0[128 * BK];
    __shared__ __attribute__((aligned(16))) unsigned short As1[128 * BK];
    __shared__ __attribute__((aligned(16))) unsigned short Bs1[128 * BK];
    int b = blockIdx.y;
    int p = blockIdx.x;                 // 0..135 -> (nt, mt), mt<=nt
    int nt = 0;
    while ((nt + 1) * (nt + 2) / 2 <= p) nt++;
    int mt = p - nt * (nt + 1) / 2;
    int n0 = nt * 128, m0 = mt * 128;
    const unsigned short* xb = xn + (size_t)b * NN * DD;

    floatx4 acc[4][4];
#pragma unroll
    for (int i = 0; i < 4; i++)
#pragma unroll
        for (int j = 0; j < 4; j++) acc[i][j] = (floatx4)0.0f;

    gemm_core(xb + (size_t)n0 * DD, DD, xb + (size_t)m0 * DD, DD, DD / BK,
              As0, Bs0, As1, Bs1, acc);

    int tid = threadIdx.x, w = tid >> 6, lane = tid & 63;
    int wr = (w >> 1) * 64, wc = (w & 1) * 64;
    int col = lane & 15, quad = lane >> 4;
    const float* nmb = norms + (size_t)b * NN;
    unsigned short* ab = attn + (size_t)b * NN * NN;
#pragma unroll
    for (int tj = 0; tj < 4; tj++) {
        int m = m0 + wc + tj * 16 + col;
        float nm = nmb[m];
#pragma unroll
        for (int ti = 0; ti < 4; ti++)
#pragma unroll
            for (int r = 0; r < 4; r++) {
                int n = n0 + wr + ti * 16 + quad * 4 + r;
                float v = acc[ti][tj][r];
                float s = sp[(size_t)n * NN + m];
                float o = (m <= n) ? s * nm * v : 0.0f;
                ab[(size_t)n * NN + m] = f2bf(o);
            }
    }
}

// ---------------------------------------------------------------------------
// Kernel 4: out[b][n][d] = (attn'[b][n][:K] . xnt[b][d][:K]) * x1[b][n][d].
// Grid 1024, one (nt,dt) per block, nt descending so long-K blocks start
// first (tail balance).
// ---------------------------------------------------------------------------
__global__ __launch_bounds__(256) void k_ctx(const unsigned short* __restrict__ attn,
                                             const unsigned short* __restrict__ xnt,
                                             const float* __restrict__ x,
                                             float* __restrict__ out) {
    __shared__ __attribute__((aligned(16))) unsigned short As0[128 * BK];
    __shared__ __attribute__((aligned(16))) unsigned short Bs0[128 * BK];
    __shared__ __attribute__((aligned(16))) unsigned short As1[128 * BK];
    __shared__ __attribute__((aligned(16))) unsigned short Bs1[128 * BK];
    int b = blockIdx.y;
    int q = blockIdx.x;                 // 0..127
    int nt = 15 - (q >> 3);
    int dt = q & 7;
    int n0 = nt * 128, d0 = dt * 128;
    const unsigned short* Ab = attn + (size_t)b * NN * NN + (size_t)n0 * NN;
    const unsigned short* Bb = xnt + (size_t)b * DD * NN + (size_t)d0 * NN;

    floatx4 acc[4][4];
#pragma unroll
    for (int i = 0; i < 4; i++)
#pragma unroll
        for (int j = 0; j < 4; j++) acc[i][j] = (floatx4)0.0f;

    gemm_core(Ab, NN, Bb, NN, (nt + 1) * 2, As0, Bs0, As1, Bs1, acc);

    int tid = threadIdx.x, w = tid >> 6, lane = tid & 63;
    int wr = (w >> 1) * 64, wc = (w & 1) * 64;
    int col = lane & 15, quad = lane >> 4;
#pragma unroll
    for (int ti = 0; ti < 4; ti++)
#pragma unroll
        for (int tj = 0; tj < 4; tj++)
#pragma unroll
            for (int r = 0; r < 4; r++) {
                int n = n0 + wr + ti * 16 + quad * 4 + r;
                int d = d0 + wc + tj * 16 + col;
                float x1 = x[((size_t)b * NN + n) * DD2 + DD + d];
                out[((size_t)b * NN + n) * DD + d] = acc[ti][tj][r] * x1;
            }
}

extern "C" void kernel_launch(void* const* d_in, const int* in_sizes, int n_in,
                              void* d_out, int out_size, void* d_ws, size_t ws_size,
                              hipStream_t stream) {
    const float* x  = (const float*)d_in[0];
    const float* sp = (const float*)d_in[1];
    float* out = (float*)d_out;

    unsigned short* xn   = (unsigned short*)d_ws;                      // 33.5 MB
    unsigned short* xnt  = xn + (size_t)NB * NN * DD;                  // 33.5 MB
    unsigned short* attn = xnt + (size_t)NB * NN * DD;                 // 67 MB
    float* norms = (float*)(attn + (size_t)NB * NN * NN);              // 64 KB

    hipLaunchKernelGGL(k_norm,      dim3(NB * NN / 4), dim3(256), 0, stream, x, xn, norms);
    hipLaunchKernelGGL(k_transpose, dim3(512, NB),     dim3(256), 0, stream, xn, xnt);
    hipLaunchKernelGGL(k_cosim,     dim3(136, NB),     dim3(256), 0, stream, xn, sp, norms, attn);
    hipLaunchKernelGGL(k_ctx,       dim3(128, NB),     dim3(256), 0, stream, attn, xnt, x, out);
}